// Round 1
// baseline (135.129 us; speedup 1.0000x reference)
//
#include <hip/hip_runtime.h>

// Problem dims (fixed): B=8, L=512, D=512, H=8. M = B*L = 4096, N = D*H = 4096, K = 512.
// out = attn_part(B,H,E) + 63.875 * vsum(B,E), flattened [b][h][e] (32768 f32).

using bf16x8 = __attribute__((ext_vector_type(8))) short;
using f32x4  = __attribute__((ext_vector_type(4))) float;

__device__ __forceinline__ unsigned short f2bf(float f) {
    union { float f; unsigned int u; } c; c.f = f;
    unsigned int u = c.u;
    u += 0x7FFFu + ((u >> 16) & 1u);   // RTNE
    return (unsigned short)(u >> 16);
}
__device__ __forceinline__ float bflo(unsigned int u) {
    union { unsigned int u; float f; } c; c.u = u << 16; return c.f;
}
__device__ __forceinline__ float bfhi(unsigned int u) {
    union { unsigned int u; float f; } c; c.u = u & 0xFFFF0000u; return c.f;
}

#define GLOAD16(gp, lp) __builtin_amdgcn_global_load_lds( \
    (const __attribute__((address_space(1))) unsigned int*)(gp), \
    (__attribute__((address_space(3))) unsigned int*)(lp), 16, 0, 0)

// ---------------- kernel 1: convert X (f32 -> bf16), z selects q/k/v ----------------
__global__ void convert_x(const float* __restrict__ x0, const float* __restrict__ x1,
                          const float* __restrict__ x2,
                          unsigned short* __restrict__ o0, unsigned short* __restrict__ o1,
                          unsigned short* __restrict__ o2, int n)
{
    const float* src = (blockIdx.z == 0) ? x0 : (blockIdx.z == 1) ? x1 : x2;
    unsigned short* dst = (blockIdx.z == 0) ? o0 : (blockIdx.z == 1) ? o1 : o2;
    int i = (blockIdx.x * blockDim.x + threadIdx.x) * 4;
    if (i < n) {
        float4 v = *(const float4*)(src + i);
        ushort4 o;
        o.x = f2bf(v.x); o.y = f2bf(v.y); o.z = f2bf(v.z); o.w = f2bf(v.w);
        *(ushort4*)(dst + i) = o;
    }
}

// ---------------- kernel 2: transpose-convert W (512x4096 f32 -> 4096x512 bf16) -----
__global__ void transpose_w(const float* __restrict__ w0, const float* __restrict__ w1,
                            const float* __restrict__ w2,
                            unsigned short* __restrict__ t0, unsigned short* __restrict__ t1,
                            unsigned short* __restrict__ t2)
{
    const float* W = (blockIdx.z == 0) ? w0 : (blockIdx.z == 1) ? w1 : w2;
    unsigned short* T = (blockIdx.z == 0) ? t0 : (blockIdx.z == 1) ? t1 : t2;
    __shared__ float tile[32][33];
    const int n0 = blockIdx.x * 32, k0 = blockIdx.y * 32;
    const int tx = threadIdx.x, ty = threadIdx.y;   // (32, 8)
    #pragma unroll
    for (int j = 0; j < 32; j += 8)
        tile[ty + j][tx] = W[(size_t)(k0 + ty + j) * 4096 + n0 + tx];
    __syncthreads();
    #pragma unroll
    for (int j = 0; j < 32; j += 8)
        T[(size_t)(n0 + ty + j) * 512 + k0 + tx] = f2bf(tile[tx][ty + j]);
}

// ---------------- kernel 3: bf16 GEMM C = A(4096x512) @ Wt(4096x512)^T + bias -------
// 128x128 tile, BK=64, 4 waves (2x2), 16x16x32 MFMA, global_load_lds staging with
// XOR-granule swizzle (linear LDS dest + inverse-swizzled global src + swizzled read).
__global__ __launch_bounds__(256) void gemm_bt(
    const unsigned short* __restrict__ a0, const unsigned short* __restrict__ a1,
    const unsigned short* __restrict__ a2,
    const unsigned short* __restrict__ w0, const unsigned short* __restrict__ w1,
    const unsigned short* __restrict__ w2,
    const float* __restrict__ b0, const float* __restrict__ b1, const float* __restrict__ b2,
    unsigned short* __restrict__ c0, unsigned short* __restrict__ c1,
    unsigned short* __restrict__ c2)
{
    const unsigned short* A;  const unsigned short* Bt; const float* bias; unsigned short* C;
    if (blockIdx.z == 0)      { A = a0; Bt = w0; bias = b0; C = c0; }
    else if (blockIdx.z == 1) { A = a1; Bt = w1; bias = b1; C = c1; }
    else                      { A = a2; Bt = w2; bias = b2; C = c2; }

    __shared__ __align__(16) unsigned short As[128 * 64];
    __shared__ __align__(16) unsigned short Bs[128 * 64];

    const int tid  = threadIdx.x;
    const int lane = tid & 63;
    const int wid  = tid >> 6;
    const int wr = wid >> 1, wc = wid & 1;
    const int row0 = blockIdx.y * 128;
    const int n0   = blockIdx.x * 128;

    // staging geometry: chunk = 1024B = 8 rows of 128B; lane covers (row=lane>>3, 16B granule)
    const int srow  = lane >> 3;             // row within chunk; == (LDS row & 7)
    const int sgran = (lane & 7) ^ srow;     // inverse-swizzled global granule

    f32x4 acc[4][4];
    #pragma unroll
    for (int i = 0; i < 4; ++i)
        #pragma unroll
        for (int j = 0; j < 4; ++j)
            acc[i][j] = (f32x4){0.f, 0.f, 0.f, 0.f};

    for (int kt = 0; kt < 8; ++kt) {
        const int k0 = kt * 64;
        #pragma unroll
        for (int i = 0; i < 4; ++i) {
            const int ch = wid * 4 + i;            // chunk 0..15
            const int trow = ch * 8 + srow;        // tile row 0..127
            GLOAD16(A  + (size_t)(row0 + trow) * 512 + k0 + sgran * 8, As + ch * 512);
            GLOAD16(Bt + (size_t)(n0   + trow) * 512 + k0 + sgran * 8, Bs + ch * 512);
        }
        __syncthreads();   // drains vmcnt before ds_read
        #pragma unroll
        for (int t = 0; t < 2; ++t) {
            // swizzled read: byte-in-row = (t*64 + (lane>>4)*16) ^ ((row&7)<<4); row&7 == lane&7
            const int kb = ((t * 4 + (lane >> 4)) ^ (lane & 7)) << 4;
            bf16x8 af[4], bfr[4];
            #pragma unroll
            for (int i = 0; i < 4; ++i) {
                const int ar = wr * 64 + i * 16 + (lane & 15);
                af[i]  = *(const bf16x8*)((const char*)As + ar * 128 + kb);
                const int br = wc * 64 + i * 16 + (lane & 15);
                bfr[i] = *(const bf16x8*)((const char*)Bs + br * 128 + kb);
            }
            #pragma unroll
            for (int i = 0; i < 4; ++i)
                #pragma unroll
                for (int j = 0; j < 4; ++j)
                    acc[i][j] = __builtin_amdgcn_mfma_f32_16x16x32_bf16(af[i], bfr[j], acc[i][j], 0, 0, 0);
        }
        __syncthreads();
    }

    // epilogue: C/D layout col = lane&15, row = (lane>>4)*4 + reg
    #pragma unroll
    for (int j = 0; j < 4; ++j) {
        const int cg = n0 + wc * 64 + j * 16 + (lane & 15);
        const float bb = bias[cg];
        #pragma unroll
        for (int i = 0; i < 4; ++i) {
            const int r0 = row0 + wr * 64 + i * 16 + (lane >> 4) * 4;
            #pragma unroll
            for (int r = 0; r < 4; ++r)
                C[(size_t)(r0 + r) * 4096 + cg] = f2bf(acc[i][j][r] + bb);
        }
    }
}

// ---------------- kernel 4: per-(b,l) 8x8 scores + softmax -> P[r][h*8+g] -----------
__global__ __launch_bounds__(64) void scores(const unsigned short* __restrict__ Q,
                                             const unsigned short* __restrict__ K,
                                             float* __restrict__ P)
{
    __shared__ __align__(16) unsigned short qs[8 * 520];
    __shared__ __align__(16) unsigned short ks[8 * 520];
    const int r = blockIdx.x;        // b*512 + l
    const int lane = threadIdx.x;    // 64
    const unsigned short* qrow = Q + (size_t)r * 4096;
    const unsigned short* krow = K + (size_t)r * 4096;
    #pragma unroll
    for (int m = 0; m < 8; ++m) {    // head m, padded stride 520 to dodge bank conflicts
        *(uint4*)(&qs[m * 520 + lane * 8]) = *(const uint4*)(qrow + m * 512 + lane * 8);
        *(uint4*)(&ks[m * 520 + lane * 8]) = *(const uint4*)(krow + m * 512 + lane * 8);
    }
    __syncthreads();

    const int h = lane >> 3, g = lane & 7;
    const unsigned short* qh = &qs[h * 520];
    const unsigned short* kg = &ks[g * 520];
    float dot = 0.f;
    #pragma unroll 4
    for (int m = 0; m < 64; ++m) {
        uint4 qa = *(const uint4*)(qh + m * 8);
        uint4 ka = *(const uint4*)(kg + m * 8);
        dot += bflo(qa.x) * bflo(ka.x) + bfhi(qa.x) * bfhi(ka.x);
        dot += bflo(qa.y) * bflo(ka.y) + bfhi(qa.y) * bfhi(ka.y);
        dot += bflo(qa.z) * bflo(ka.z) + bfhi(qa.z) * bfhi(ka.z);
        dot += bflo(qa.w) * bflo(ka.w) + bfhi(qa.w) * bfhi(ka.w);
    }
    float s = dot * 0.04419417382415922f;   // 1/sqrt(512)
    float mx = s;
    mx = fmaxf(mx, __shfl_xor(mx, 1));
    mx = fmaxf(mx, __shfl_xor(mx, 2));
    mx = fmaxf(mx, __shfl_xor(mx, 4));
    float e = __expf(s - mx);
    float sm = e;
    sm += __shfl_xor(sm, 1);
    sm += __shfl_xor(sm, 2);
    sm += __shfl_xor(sm, 4);
    P[(size_t)r * 64 + lane] = e / sm;
}

// ---------------- kernel 5: zero accumulators ---------------------------------------
__global__ void zero_f(float* __restrict__ p, int n)
{
    int i = blockIdx.x * blockDim.x + threadIdx.x;
    if (i < n) p[i] = 0.f;
}

// ---------------- kernel 6: attn_part + vsum (atomic partial reductions) ------------
__global__ __launch_bounds__(256) void attn_vsum(const float* __restrict__ P,
                                                 const unsigned short* __restrict__ V,
                                                 float* __restrict__ attn,
                                                 float* __restrict__ vsum)
{
    // grid (8 b, 32 lchunk), block 256; each thread owns 2 e-columns, 16 l's
    __shared__ float Pl[16 * 64];
    const int b = blockIdx.x, lc = blockIdx.y;
    const int tid = threadIdx.x;
    const float* Pg = P + ((size_t)b * 512 + lc * 16) * 64;
    #pragma unroll
    for (int i = 0; i < 4; ++i) Pl[i * 256 + tid] = Pg[i * 256 + tid];
    __syncthreads();

    const int e0 = tid * 2;
    float acc0[8], acc1[8];
    #pragma unroll
    for (int h = 0; h < 8; ++h) { acc0[h] = 0.f; acc1[h] = 0.f; }
    float vs0 = 0.f, vs1 = 0.f;

    for (int l = 0; l < 16; ++l) {
        const unsigned short* vrow = V + ((size_t)(b * 512 + lc * 16 + l)) * 4096;
        #pragma unroll
        for (int g = 0; g < 8; ++g) {
            unsigned int u = *(const unsigned int*)(vrow + g * 512 + e0);
            float v0 = bflo(u), v1 = bfhi(u);
            vs0 += v0; vs1 += v1;
            #pragma unroll
            for (int h = 0; h < 8; ++h) {
                float p = Pl[l * 64 + h * 8 + g];   // uniform -> LDS broadcast
                acc0[h] += p * v0; acc1[h] += p * v1;
            }
        }
    }
    float* ap = attn + (size_t)b * 4096;
    #pragma unroll
    for (int h = 0; h < 8; ++h) {
        atomicAdd(&ap[h * 512 + e0],     acc0[h]);
        atomicAdd(&ap[h * 512 + e0 + 1], acc1[h]);
    }
    atomicAdd(&vsum[b * 512 + e0],     vs0);
    atomicAdd(&vsum[b * 512 + e0 + 1], vs1);
}

// ---------------- kernel 7: out = attn + 63.875 * vsum ------------------------------
__global__ void finalize(const float* __restrict__ attn, const float* __restrict__ vsum,
                         float* __restrict__ out, int n)
{
    int i = blockIdx.x * blockDim.x + threadIdx.x;
    if (i < n) {
        int b = i >> 12, e = i & 511;
        out[i] = attn[i] + 63.875f * vsum[b * 512 + e];
    }
}

extern "C" void kernel_launch(void* const* d_in, const int* in_sizes, int n_in,
                              void* d_out, int out_size, void* d_ws, size_t ws_size,
                              hipStream_t stream)
{
    const float* queries = (const float*)d_in[0];
    const float* keys    = (const float*)d_in[1];
    const float* values  = (const float*)d_in[2];
    const float* Wq      = (const float*)d_in[3];
    const float* bq      = (const float*)d_in[4];
    const float* Wk      = (const float*)d_in[5];
    const float* bk      = (const float*)d_in[6];
    const float* Wv      = (const float*)d_in[7];
    const float* bv      = (const float*)d_in[8];
    // d_in[9] = attn_mask (falsy scalar, unused)

    // workspace layout (needs ~121.2 MB)
    unsigned short* xq  = (unsigned short*)d_ws;
    unsigned short* xk  = xq  + (1u << 21);
    unsigned short* xv  = xk  + (1u << 21);
    unsigned short* wtq = xv  + (1u << 21);
    unsigned short* wtk = wtq + (1u << 21);
    unsigned short* wtv = wtk + (1u << 21);
    unsigned short* Q   = wtv + (1u << 21);
    unsigned short* Kb  = Q   + (1u << 24);
    unsigned short* Vb  = Kb  + (1u << 24);
    float* P    = (float*)(Vb + (1u << 24));
    float* attn = P + 4096 * 64;
    float* vsum = attn + 32768;

    zero_f<<<dim3(144), 256, 0, stream>>>(attn, 36864);  // attn + vsum contiguous
    convert_x<<<dim3(2048, 1, 3), 256, 0, stream>>>(queries, keys, values, xq, xk, xv, 2097152);
    transpose_w<<<dim3(128, 16, 3), dim3(32, 8), 0, stream>>>(Wq, Wk, Wv, wtq, wtk, wtv);
    gemm_bt<<<dim3(32, 32, 3), 256, 0, stream>>>(xq, xk, xv, wtq, wtk, wtv,
                                                 bq, bk, bv, Q, Kb, Vb);
    scores<<<dim3(4096), 64, 0, stream>>>(Q, Kb, P);
    attn_vsum<<<dim3(8, 32), 256, 0, stream>>>(P, Vb, attn, vsum);
    finalize<<<dim3(128), 256, 0, stream>>>(attn, vsum, (float*)d_out, 32768);
}